// Round 1
// baseline (150.197 us; speedup 1.0000x reference)
//
#include <hip/hip_runtime.h>

#define LRELU(x) ((x) > 0.f ? (x) : 0.01f * (x))

// ws layout (float offsets)
#define H2_OFF    0          // [8][16][512]   h, layout [n][pix][ci]
#define T1_OFF    65536      // [8][512]
#define T2_OFF    69632      // [8][512]
#define PK_OFF    73728      // [8][2048]
#define PB_OFF    90112      // [8][512]
#define D_OFF     94208      // [8][9][2048]   dw2 matmul (no bias)
#define WEFF_OFF  241664     // [8][128][3][3][4][4]  ([n][Q][ky][kx][i][o])

// h[n][pix][co] = lrelu( sum_ci dw1_w[co][ci]*style[n][ci][pix] + dw1_b[co] )
__global__ __launch_bounds__(256) void k1_h(const float* __restrict__ style,
                                            const float* __restrict__ w,
                                            const float* __restrict__ b,
                                            float* __restrict__ h2) {
  int blk = blockIdx.x; int n = blk >> 4; int pix = blk & 15;
  __shared__ float s[512];
  const float* sp = style + n * 8192 + pix;
  for (int i = threadIdx.x; i < 512; i += 256) s[i] = sp[i * 16];
  __syncthreads();
  for (int co = threadIdx.x; co < 512; co += 256) {
    const float4* wr = (const float4*)(w + co * 512);
    float acc = b[co];
#pragma unroll 8
    for (int k = 0; k < 128; ++k) {
      float4 wv = wr[k];
      acc += wv.x * s[4*k+0] + wv.y * s[4*k+1] + wv.z * s[4*k+2] + wv.w * s[4*k+3];
    }
    h2[n * 8192 + pix * 512 + co] = LRELU(acc);
  }
}

// t1[n][co] = lrelu(pk1(s_pool)), t2[n][co] = lrelu(pb1(s_pool)); s_pool recomputed per block
__global__ __launch_bounds__(256) void k3_t(const float* __restrict__ style,
    const float* __restrict__ w1, const float* __restrict__ b1,
    const float* __restrict__ w1b, const float* __restrict__ b1b,
    float* __restrict__ t1, float* __restrict__ t2) {
  int n = blockIdx.x >> 1; int which = blockIdx.x & 1;
  __shared__ float s[512];
  for (int ci = threadIdx.x; ci < 512; ci += 256) {
    const float4* r = (const float4*)(style + n * 8192 + ci * 16);
    float4 a = r[0], bb = r[1], c = r[2], d = r[3];
    s[ci] = (a.x+a.y+a.z+a.w + bb.x+bb.y+bb.z+bb.w + c.x+c.y+c.z+c.w + d.x+d.y+d.z+d.w) * (1.f/16.f);
  }
  __syncthreads();
  const float* w  = which ? w1b : w1;
  const float* bv = which ? b1b : b1;
  float* out = which ? t2 : t1;
  for (int co = threadIdx.x; co < 512; co += 256) {
    const float4* wr = (const float4*)(w + co * 512);
    float acc = bv[co];
#pragma unroll 8
    for (int k = 0; k < 128; ++k) {
      float4 wv = wr[k];
      acc += wv.x * s[4*k+0] + wv.y * s[4*k+1] + wv.z * s[4*k+2] + wv.w * s[4*k+3];
    }
    out[n * 512 + co] = LRELU(acc);
  }
}

// pk[n][o2] = pk2(t1)+b ; pb[n][co] = pb2(t2)+b
__global__ __launch_bounds__(256) void k4_pkpb(const float* __restrict__ t1, const float* __restrict__ t2,
    const float* __restrict__ w2, const float* __restrict__ b2,
    const float* __restrict__ w2b, const float* __restrict__ b2b,
    float* __restrict__ pk, float* __restrict__ pb) {
  int n = blockIdx.x / 10; int tile = blockIdx.x % 10;
  bool isPb = tile >= 8;
  __shared__ float s[512];
  const float* src = (isPb ? t2 : t1) + n * 512;
  for (int i = threadIdx.x; i < 512; i += 256) s[i] = src[i];
  __syncthreads();
  int o = (isPb ? tile - 8 : tile) * 256 + threadIdx.x;
  const float* w = isPb ? w2b : w2;
  float acc = (isPb ? b2b : b2)[o];
  const float4* wr = (const float4*)(w + o * 512);
#pragma unroll 8
  for (int k = 0; k < 128; ++k) {
    float4 wv = wr[k];
    acc += wv.x * s[4*k+0] + wv.y * s[4*k+1] + wv.z * s[4*k+2] + wv.w * s[4*k+3];
  }
  if (isPb) pb[n * 512 + o] = acc; else pk[n * 2048 + o] = acc;
}

// Split-K matmul: D[n][p][o2] += sum_{cik chunk} h_win * dw2_w  (bias added later)
__global__ __launch_bounds__(256) void k5_dw2(const float* __restrict__ h2,
    const float* __restrict__ w2, float* __restrict__ D) {
  int b = blockIdx.x; int bo = b & 7; int kc = (b >> 3) & 7; int n = b >> 6;
  __shared__ float A[9][256];
  for (int idx = threadIdx.x; idx < 9 * 256; idx += 256) {
    int p = idx >> 8; int kk = idx & 255;
    int cik = kc * 256 + kk; int ci = cik >> 2; int kyx = cik & 3;
    int ky = kyx >> 1, kx = kyx & 1;
    int pix = (p / 3 + ky) * 4 + (p % 3 + kx);
    A[p][kk] = h2[n * 8192 + pix * 512 + ci];
  }
  __syncthreads();
  int o2 = bo * 256 + threadIdx.x;
  const float4* wr = (const float4*)(w2 + o2 * 2048 + kc * 256);
  float acc[9];
#pragma unroll
  for (int p = 0; p < 9; ++p) acc[p] = 0.f;
  for (int k = 0; k < 64; ++k) {
    float4 wv = wr[k];
#pragma unroll
    for (int p = 0; p < 9; ++p) {
      float4 a = *(const float4*)&A[p][4 * k];
      acc[p] += wv.x * a.x + wv.y * a.y + wv.z * a.z + wv.w * a.w;
    }
  }
#pragma unroll
  for (int p = 0; p < 9; ++p) atomicAdd(&D[(n * 9 + p) * 2048 + o2], acc[p]);
}

// w_eff[n][Q][ky][kx][i][o] = sum_j pk[n][16Q+4o+j] * (D[n][p][16Q+4j+i] + dw2_b[16Q+4j+i])
__global__ __launch_bounds__(256) void k6_weff(const float* __restrict__ D,
    const float* __restrict__ pk, const float* __restrict__ b2,
    float* __restrict__ weff) {
  int idx = blockIdx.x * 256 + threadIdx.x;
  int o = idx & 3; int i = (idx >> 2) & 3;
  int r = idx >> 4; int kx = r % 3; r /= 3; int ky = r % 3; r /= 3;
  int Q = r & 127; int n = r >> 7;
  int p = ky * 3 + kx;
  const float* Dp  = D + (n * 9 + p) * 2048 + 16 * Q;
  const float* pkp = pk + n * 2048 + 16 * Q + 4 * o;
  const float* bp  = b2 + 16 * Q;
  float sum = 0.f;
#pragma unroll
  for (int j = 0; j < 4; ++j) sum += pkp[j] * (Dp[4 * j + i] + bp[4 * j + i]);
  weff[idx] = sum;
}

// Fused grouped 3x3 conv with folded pointwise. Block = (n, Q, 16-row tile).
__global__ __launch_bounds__(256) void k7_main(const float* __restrict__ x,
    const float* __restrict__ weff, const float* __restrict__ pb,
    float* __restrict__ out) {
  int b = blockIdx.x; int rt = b & 3; int Q = (b >> 2) & 127; int n = b >> 9;
  __shared__ float xs[4][18][67];  // stride 67: conflict-minimal
  __shared__ float wsm[144];       // [ky][kx][i][o]
  __shared__ float bs[4];
  if (threadIdx.x < 144) wsm[threadIdx.x] = weff[(n * 128 + Q) * 144 + threadIdx.x];
  if (threadIdx.x >= 144 && threadIdx.x < 148)
    bs[threadIdx.x - 144] = pb[n * 512 + Q * 4 + (threadIdx.x - 144)];
  const float* base = x + (size_t)(n * 512 + Q * 4) * 4096;
  for (int idx = threadIdx.x; idx < 4 * 18 * 66; idx += 256) {
    int c = idx % 66; int t = idx / 66; int rr = t % 18; int ch = t / 18;
    int gy = rt * 16 + rr - 1; gy = gy < 0 ? 1 : (gy > 63 ? 62 : gy);  // reflect
    int gx = c - 1;            gx = gx < 0 ? 1 : (gx > 63 ? 62 : gx);
    xs[ch][rr][c] = base[ch * 4096 + gy * 64 + gx];
  }
  __syncthreads();
  int row = threadIdx.x >> 4; int cq = threadIdx.x & 15;
  float acc[4][4];  // [o][px]
#pragma unroll
  for (int o = 0; o < 4; ++o)
#pragma unroll
    for (int px = 0; px < 4; ++px) acc[o][px] = bs[o];
#pragma unroll
  for (int ky = 0; ky < 3; ++ky) {
#pragma unroll
    for (int i = 0; i < 4; ++i) {
      const float* rp = &xs[i][row + ky][4 * cq];
      float v[6];
#pragma unroll
      for (int t6 = 0; t6 < 6; ++t6) v[t6] = rp[t6];
#pragma unroll
      for (int kx = 0; kx < 3; ++kx) {
        const float* wp = &wsm[((ky * 3 + kx) * 4 + i) * 4];
        float w0 = wp[0], w1 = wp[1], w2 = wp[2], w3 = wp[3];
#pragma unroll
        for (int px = 0; px < 4; ++px) {
          float xv = v[px + kx];
          acc[0][px] += w0 * xv;
          acc[1][px] += w1 * xv;
          acc[2][px] += w2 * xv;
          acc[3][px] += w3 * xv;
        }
      }
    }
  }
  int gy = rt * 16 + row;
#pragma unroll
  for (int o = 0; o < 4; ++o) {
    float4 st; st.x = acc[o][0]; st.y = acc[o][1]; st.z = acc[o][2]; st.w = acc[o][3];
    *(float4*)&out[(((size_t)(n * 512 + Q * 4 + o)) * 64 + gy) * 64 + 4 * cq] = st;
  }
}

extern "C" void kernel_launch(void* const* d_in, const int* in_sizes, int n_in,
                              void* d_out, int out_size, void* d_ws, size_t ws_size,
                              hipStream_t stream) {
  const float* style = (const float*)d_in[0];
  const float* pred  = (const float*)d_in[1];
  const float* dw1_w = (const float*)d_in[2];
  const float* dw1_b = (const float*)d_in[3];
  const float* dw2_w = (const float*)d_in[4];
  const float* dw2_b = (const float*)d_in[5];
  const float* pk1_w = (const float*)d_in[6];
  const float* pk1_b = (const float*)d_in[7];
  const float* pk2_w = (const float*)d_in[8];
  const float* pk2_b = (const float*)d_in[9];
  const float* pb1_w = (const float*)d_in[10];
  const float* pb1_b = (const float*)d_in[11];
  const float* pb2_w = (const float*)d_in[12];
  const float* pb2_b = (const float*)d_in[13];
  float* ws   = (float*)d_ws;
  float* h2   = ws + H2_OFF;
  float* t1   = ws + T1_OFF;
  float* t2   = ws + T2_OFF;
  float* pk   = ws + PK_OFF;
  float* pb   = ws + PB_OFF;
  float* D    = ws + D_OFF;
  float* weff = ws + WEFF_OFF;
  float* out  = (float*)d_out;

  hipMemsetAsync(D, 0, (size_t)8 * 9 * 2048 * sizeof(float), stream);
  k1_h  <<<128,  256, 0, stream>>>(style, dw1_w, dw1_b, h2);
  k3_t  <<<16,   256, 0, stream>>>(style, pk1_w, pk1_b, pb1_w, pb1_b, t1, t2);
  k4_pkpb<<<80,  256, 0, stream>>>(t1, t2, pk2_w, pk2_b, pb2_w, pb2_b, pk, pb);
  k5_dw2<<<512,  256, 0, stream>>>(h2, dw2_w, D);
  k6_weff<<<576, 256, 0, stream>>>(D, pk, dw2_b, weff);
  k7_main<<<4096,256, 0, stream>>>(pred, weff, pb, out);
}